// Round 1
// baseline (526.261 us; speedup 1.0000x reference)
//
#include <hip/hip_runtime.h>

// DistSparseMoe: B=4 S=4096 H=2048 E=8, T=16384 tokens, all inputs f32.
// out[i,:] = (x[order[i],:] @ We + be) * best_p[i]
//   best   = argmax(softmax(x@Wg+bg)) per token (f32 exact — argmax flips are fatal)
//   order  = STABLE argsort(best)  (stable counting sort: chunk hist -> scan -> ballot rank)
//   GEMM in bf16 MFMA (error ~1e-2 absmax << 0.079 threshold)

#define T_TOK 16384
#define H_DIM 2048

typedef __attribute__((ext_vector_type(8))) short bf16x8;
typedef __attribute__((ext_vector_type(4))) float f32x4;

__device__ __forceinline__ unsigned short f2bf(float f) {
  unsigned u = __builtin_bit_cast(unsigned, f);
  u += 0x7fffu + ((u >> 16) & 1u);   // RNE; inputs are finite normals
  return (unsigned short)(u >> 16);
}
__device__ __forceinline__ unsigned pk2(float a, float b) {
  return (unsigned)f2bf(a) | ((unsigned)f2bf(b) << 16);
}

// ---- WgT[e][h] = Wg[h][e]  (f32, 8x2048) ----
__global__ void transpose_wg_kernel(const float* __restrict__ Wg, float* __restrict__ WgT) {
  int i = blockIdx.x * 256 + threadIdx.x;           // 16384
  WgT[i] = Wg[(i & 2047) * 8 + (i >> 11)];
}

// ---- WeT[n][k] = bf16(We[k][n])  (2048x2048) ----
__global__ void transpose_we_kernel(const float* __restrict__ We, unsigned short* __restrict__ WeT) {
  __shared__ float tile[32][33];
  int n0 = blockIdx.x * 32, k0 = blockIdx.y * 32;
  int tx = threadIdx.x, ty = threadIdx.y;           // 32 x 8
  #pragma unroll
  for (int r = 0; r < 32; r += 8)
    tile[ty + r][tx] = We[(size_t)(k0 + ty + r) * H_DIM + n0 + tx];
  __syncthreads();
  #pragma unroll
  for (int r = 0; r < 32; r += 8)
    WeT[(size_t)(n0 + ty + r) * H_DIM + k0 + tx] = f2bf(tile[tx][ty + r]);
}

// ---- router: logits (f32), softmax, argmax, per-chunk expert counts ----
__global__ __launch_bounds__(256) void router_kernel(
    const float* __restrict__ x, const float* __restrict__ WgT,
    const float* __restrict__ bg, int* __restrict__ best,
    float* __restrict__ bestp, int* __restrict__ bcnt)
{
  __shared__ int cnt[8];
  const int tid = threadIdx.x;
  if (tid < 8) cnt[tid] = 0;
  __syncthreads();
  const int lane = tid & 63;
  const int wave = tid >> 6;
  const int tbase = blockIdx.x * 64 + wave * 16;    // block = 64-token chunk
  float bgv[8];
  #pragma unroll
  for (int e = 0; e < 8; ++e) bgv[e] = bg[e];

  for (int it = 0; it < 16; it += 2) {
    const int t0 = tbase + it;
    const float4* xp0 = (const float4*)(x + (size_t)t0 * H_DIM);
    const float4* xp1 = (const float4*)(x + (size_t)(t0 + 1) * H_DIM);
    float l0[8] = {0,0,0,0,0,0,0,0};
    float l1[8] = {0,0,0,0,0,0,0,0};
    #pragma unroll
    for (int j = 0; j < 8; ++j) {
      float4 a0 = xp0[j * 64 + lane];
      float4 a1 = xp1[j * 64 + lane];
      #pragma unroll
      for (int e = 0; e < 8; ++e) {
        float4 wv = ((const float4*)(WgT + e * H_DIM))[j * 64 + lane];
        l0[e] += a0.x*wv.x + a0.y*wv.y + a0.z*wv.z + a0.w*wv.w;
        l1[e] += a1.x*wv.x + a1.y*wv.y + a1.z*wv.z + a1.w*wv.w;
      }
    }
    #pragma unroll
    for (int e = 0; e < 8; ++e) {
      #pragma unroll
      for (int s = 1; s < 64; s <<= 1) {
        l0[e] += __shfl_xor(l0[e], s, 64);
        l1[e] += __shfl_xor(l1[e], s, 64);
      }
    }
    // all lanes hold full logits for both tokens; compute redundantly, write predicated
    float m0 = l0[0] + bgv[0]; int b0 = 0;
    float m1 = l1[0] + bgv[0]; int b1 = 0;
    #pragma unroll
    for (int e = 1; e < 8; ++e) {
      float v0 = l0[e] + bgv[e]; if (v0 > m0) { m0 = v0; b0 = e; }   // strict > = first max
      float v1 = l1[e] + bgv[e]; if (v1 > m1) { m1 = v1; b1 = e; }
    }
    float s0 = 0.f, s1 = 0.f;
    #pragma unroll
    for (int e = 0; e < 8; ++e) {
      s0 += __expf(l0[e] + bgv[e] - m0);
      s1 += __expf(l1[e] + bgv[e] - m1);
    }
    float p0 = 1.f / s0, p1 = 1.f / s1;
    if (lane == 0) { best[t0] = b0;     bestp[t0] = p0;     atomicAdd(&cnt[b0], 1); }
    if (lane == 1) { best[t0 + 1] = b1; bestp[t0 + 1] = p1; atomicAdd(&cnt[b1], 1); }
  }
  __syncthreads();
  if (tid < 8) bcnt[blockIdx.x * 8 + tid] = cnt[tid];
}

// ---- scan: per-(chunk,expert) exclusive prefix + expert bases ----
__global__ void scan_kernel(const int* __restrict__ bcnt, int* __restrict__ bstart) {
  __shared__ int st[256 * 8];
  __shared__ int tot[8];
  __shared__ int ebase[8];
  int tid = threadIdx.x;
  if (tid < 8) {
    int run = 0;
    for (int b = 0; b < 256; ++b) { st[b * 8 + tid] = run; run += bcnt[b * 8 + tid]; }
    tot[tid] = run;
  }
  __syncthreads();
  if (tid == 0) {
    int run = 0;
    for (int e = 0; e < 8; ++e) { ebase[e] = run; run += tot[e]; }
  }
  __syncthreads();
  for (int i = tid; i < 2048; i += blockDim.x) bstart[i] = st[i] + ebase[i & 7];
}

// ---- order: stable rank within 64-token chunk via ballot ----
__global__ void order_kernel(const int* __restrict__ best, const int* __restrict__ bstart,
                             int* __restrict__ order) {
  __shared__ int bs[8];
  int lane = threadIdx.x;                            // 64 threads = 1 wave
  if (lane < 8) bs[lane] = bstart[blockIdx.x * 8 + lane];
  __syncthreads();
  int t = blockIdx.x * 64 + lane;
  int e = best[t];
  unsigned long long lt = (1ull << lane) - 1ull;
  int rank = 0;
  #pragma unroll
  for (int q = 0; q < 8; ++q) {
    unsigned long long m = __ballot(e == q);
    if (e == q) rank = __popcll(m & lt);
  }
  order[bs[e] + rank] = t;
}

// ---- GEMM: out[m0+r] = (x[order[m0+r]] @ WeT^T + be) * bestp[m0+r] ----
// 128x128 tile, BK=32, 4 waves (2x2), mfma 16x16x32 bf16, reg-staged LDS.
__global__ __launch_bounds__(256) void gemm_kernel(
    const float* __restrict__ x, const unsigned short* __restrict__ WeT,
    const float* __restrict__ be, const int* __restrict__ order,
    const float* __restrict__ bestp, float* __restrict__ out)
{
  __shared__ unsigned short As[128][40];   // pad 32->40 to break bank stride
  __shared__ unsigned short Bs[128][40];
  __shared__ int rows[128];
  __shared__ float scales[128];

  const int tid = threadIdx.x;
  const int tileM = blockIdx.x >> 4;
  const int tileN = blockIdx.x & 15;
  const int m0 = tileM * 128, n0 = tileN * 128;

  if (tid < 128) { rows[tid] = order[m0 + tid]; scales[tid] = bestp[m0 + tid]; }
  __syncthreads();

  const int lane = tid & 63;
  const int wave = tid >> 6;
  const int wm = (wave >> 1) * 64;
  const int wn = (wave & 1) * 64;
  const int fr = lane & 15;
  const int fq = lane >> 4;

  const int sr = tid >> 1;             // staging row 0..127
  const int sc = (tid & 1) * 16;       // staging col 0 or 16
  const float* aptr = x + (size_t)rows[sr] * H_DIM + sc;          // gathered A row (f32)
  const unsigned short* bptr = WeT + (size_t)(n0 + sr) * H_DIM + sc;

  f32x4 acc[4][4] = {};

  for (int kk = 0; kk < H_DIM; kk += 32) {
    float4 v0 = ((const float4*)(aptr + kk))[0];
    float4 v1 = ((const float4*)(aptr + kk))[1];
    float4 v2 = ((const float4*)(aptr + kk))[2];
    float4 v3 = ((const float4*)(aptr + kk))[3];
    uint4 b0 = ((const uint4*)(bptr + kk))[0];
    uint4 b1 = ((const uint4*)(bptr + kk))[1];
    __syncthreads();   // previous tile's frag reads done
    *(uint4*)&As[sr][sc]     = make_uint4(pk2(v0.x,v0.y), pk2(v0.z,v0.w), pk2(v1.x,v1.y), pk2(v1.z,v1.w));
    *(uint4*)&As[sr][sc + 8] = make_uint4(pk2(v2.x,v2.y), pk2(v2.z,v2.w), pk2(v3.x,v3.y), pk2(v3.z,v3.w));
    *(uint4*)&Bs[sr][sc]     = b0;
    *(uint4*)&Bs[sr][sc + 8] = b1;
    __syncthreads();   // tile visible
    bf16x8 af[4], bf[4];
    #pragma unroll
    for (int i = 0; i < 4; ++i) {
      af[i] = *(const bf16x8*)&As[wm + i * 16 + fr][fq * 8];
      bf[i] = *(const bf16x8*)&Bs[wn + i * 16 + fr][fq * 8];
    }
    #pragma unroll
    for (int mi = 0; mi < 4; ++mi)
      #pragma unroll
      for (int ni = 0; ni < 4; ++ni)
        acc[mi][ni] = __builtin_amdgcn_mfma_f32_16x16x32_bf16(af[mi], bf[ni], acc[mi][ni], 0, 0, 0);
  }

  float bev[4];
  #pragma unroll
  for (int ni = 0; ni < 4; ++ni) bev[ni] = be[n0 + wn + ni * 16 + fr];

  #pragma unroll
  for (int mi = 0; mi < 4; ++mi) {
    #pragma unroll
    for (int ni = 0; ni < 4; ++ni) {
      const int col = n0 + wn + ni * 16 + fr;
      #pragma unroll
      for (int r = 0; r < 4; ++r) {
        const int lrow = wm + mi * 16 + fq * 4 + r;   // C/D: row=(lane>>4)*4+reg, col=lane&15
        out[(size_t)(m0 + lrow) * H_DIM + col] = (acc[mi][ni][r] + bev[ni]) * scales[lrow];
      }
    }
  }
}

extern "C" void kernel_launch(void* const* d_in, const int* in_sizes, int n_in,
                              void* d_out, int out_size, void* d_ws, size_t ws_size,
                              hipStream_t stream)
{
  const float* x  = (const float*)d_in[0];
  const float* Wg = (const float*)d_in[1];
  const float* bg = (const float*)d_in[2];
  const float* We = (const float*)d_in[3];
  const float* be = (const float*)d_in[4];
  float* out = (float*)d_out;

  char* w = (char*)d_ws;
  int*   best   = (int*)(w);                       // 64 KB
  float* bestp  = (float*)(w + (64 << 10));        // 64 KB
  int*   order  = (int*)(w + (128 << 10));         // 64 KB
  int*   bcnt   = (int*)(w + (192 << 10));         // 8 KB
  int*   bstart = (int*)(w + (200 << 10));         // 8 KB
  float* WgT    = (float*)(w + (208 << 10));       // 64 KB
  unsigned short* WeT = (unsigned short*)(w + (272 << 10));  // 8 MB  (total ~8.3 MB)

  transpose_wg_kernel<<<64, 256, 0, stream>>>(Wg, WgT);
  transpose_we_kernel<<<dim3(64, 64), dim3(32, 8), 0, stream>>>(We, WeT);
  router_kernel<<<256, 256, 0, stream>>>(x, WgT, bg, best, bestp, bcnt);
  scan_kernel<<<1, 256, 0, stream>>>(bcnt, bstart);
  order_kernel<<<256, 64, 0, stream>>>(best, bstart, order);
  gemm_kernel<<<2048, 256, 0, stream>>>(x, WeT, be, order, bestp, out);
}

// Round 2
// 475.103 us; speedup vs baseline: 1.1077x; 1.1077x over previous
//
#include <hip/hip_runtime.h>

// DistSparseMoe: B=4 S=4096 H=2048 E=8, T=16384 tokens, f32 inputs.
// out[i,:] = (x[order[i],:] @ We + be) * best_p[i]
// Round 2: pre-gathered bf16 A + m97-structure GEMM (global_load_lds x16),
//          full-occupancy router, parallel scan.

#define T_TOK 16384
#define H_DIM 2048
#define BM 128
#define BN 128
#define BK 64

typedef __attribute__((ext_vector_type(8))) short bf16x8;
typedef __attribute__((ext_vector_type(4))) float f32x4;

__device__ __forceinline__ unsigned short f2bf(float f) {
  unsigned u = __builtin_bit_cast(unsigned, f);
  u += 0x7fffu + ((u >> 16) & 1u);   // RNE; inputs are finite normals
  return (unsigned short)(u >> 16);
}
__device__ __forceinline__ unsigned pk2(float a, float b) {
  return (unsigned)f2bf(a) | ((unsigned)f2bf(b) << 16);
}

// async global->LDS, 16B per lane; lds dest must be wave-uniform base (+lane*16 implicit)
#define GLOAD16(gp, lp) \
  __builtin_amdgcn_global_load_lds((const __attribute__((address_space(1))) unsigned int*)(gp), \
                                   (__attribute__((address_space(3))) unsigned int*)(lp), 16, 0, 0)

// ---- WgT[e][h] = Wg[h][e]  (f32, 8x2048) ----
__global__ void transpose_wg_kernel(const float* __restrict__ Wg, float* __restrict__ WgT) {
  int i = blockIdx.x * 256 + threadIdx.x;           // 16384
  WgT[i] = Wg[(i & 2047) * 8 + (i >> 11)];
}

// ---- WeT[n][k] = bf16(We[k][n])  (2048x2048) ----
__global__ void transpose_we_kernel(const float* __restrict__ We, unsigned short* __restrict__ WeT) {
  __shared__ float tile[32][33];
  int n0 = blockIdx.x * 32, k0 = blockIdx.y * 32;
  int tx = threadIdx.x, ty = threadIdx.y;           // 32 x 8
  #pragma unroll
  for (int r = 0; r < 32; r += 8)
    tile[ty + r][tx] = We[(size_t)(k0 + ty + r) * H_DIM + n0 + tx];
  __syncthreads();
  #pragma unroll
  for (int r = 0; r < 32; r += 8)
    WeT[(size_t)(n0 + ty + r) * H_DIM + k0 + tx] = f2bf(tile[tx][ty + r]);
}

// ---- router: f32 logits, softmax, argmax; 2 tokens per wave (full occupancy) ----
__global__ __launch_bounds__(256) void router_kernel(
    const float* __restrict__ x, const float* __restrict__ WgT,
    const float* __restrict__ bg, int* __restrict__ best,
    float* __restrict__ bestp, int* __restrict__ bcnt)
{
  const int tid = threadIdx.x;
  const int lane = tid & 63;
  const int wave = tid >> 6;
  const int t0 = blockIdx.x * 8 + wave * 2;         // this wave's token pair
  float bgv[8];
  #pragma unroll
  for (int e = 0; e < 8; ++e) bgv[e] = bg[e];

  const float4* xp0 = (const float4*)(x + (size_t)t0 * H_DIM);
  const float4* xp1 = (const float4*)(x + (size_t)(t0 + 1) * H_DIM);
  float l0[8] = {0,0,0,0,0,0,0,0};
  float l1[8] = {0,0,0,0,0,0,0,0};
  #pragma unroll
  for (int j = 0; j < 8; ++j) {
    float4 a0 = xp0[j * 64 + lane];
    float4 a1 = xp1[j * 64 + lane];
    #pragma unroll
    for (int e = 0; e < 8; ++e) {
      float4 wv = ((const float4*)(WgT + e * H_DIM))[j * 64 + lane];
      l0[e] += a0.x*wv.x + a0.y*wv.y + a0.z*wv.z + a0.w*wv.w;
      l1[e] += a1.x*wv.x + a1.y*wv.y + a1.z*wv.z + a1.w*wv.w;
    }
  }
  #pragma unroll
  for (int e = 0; e < 8; ++e) {
    #pragma unroll
    for (int s = 1; s < 64; s <<= 1) {
      l0[e] += __shfl_xor(l0[e], s, 64);
      l1[e] += __shfl_xor(l1[e], s, 64);
    }
  }
  float m0 = l0[0] + bgv[0]; int b0 = 0;
  float m1 = l1[0] + bgv[0]; int b1 = 0;
  #pragma unroll
  for (int e = 1; e < 8; ++e) {
    float v0 = l0[e] + bgv[e]; if (v0 > m0) { m0 = v0; b0 = e; }  // strict > = first max
    float v1 = l1[e] + bgv[e]; if (v1 > m1) { m1 = v1; b1 = e; }
  }
  float s0 = 0.f, s1 = 0.f;
  #pragma unroll
  for (int e = 0; e < 8; ++e) {
    s0 += __expf(l0[e] + bgv[e] - m0);
    s1 += __expf(l1[e] + bgv[e] - m1);
  }
  const int chunk = t0 >> 6;
  if (lane == 0) { best[t0] = b0;     bestp[t0] = 1.f / s0;     atomicAdd(&bcnt[chunk * 8 + b0], 1); }
  if (lane == 1) { best[t0 + 1] = b1; bestp[t0 + 1] = 1.f / s1; atomicAdd(&bcnt[chunk * 8 + b1], 1); }
}

// ---- scan: 8 waves, wave e scans expert e over 256 chunks ----
__global__ __launch_bounds__(512) void scan_kernel(const int* __restrict__ bcnt,
                                                   int* __restrict__ bstart) {
  __shared__ int tot[8];
  __shared__ int ebase[8];
  const int tid = threadIdx.x, e = tid >> 6, lane = tid & 63;
  int v[4], s = 0;
  #pragma unroll
  for (int j = 0; j < 4; ++j) { v[j] = bcnt[(lane * 4 + j) * 8 + e]; s += v[j]; }
  int inc = s;
  #pragma unroll
  for (int d = 1; d < 64; d <<= 1) { int t = __shfl_up(inc, d, 64); if (lane >= d) inc += t; }
  int excl = inc - s;
  if (lane == 63) tot[e] = inc;
  __syncthreads();
  if (tid == 0) { int run = 0; for (int q = 0; q < 8; ++q) { ebase[q] = run; run += tot[q]; } }
  __syncthreads();
  int run = ebase[e] + excl;
  #pragma unroll
  for (int j = 0; j < 4; ++j) { bstart[(lane * 4 + j) * 8 + e] = run; run += v[j]; }
}

// ---- order: stable rank within 64-token chunk via ballot ----
__global__ void order_kernel(const int* __restrict__ best, const int* __restrict__ bstart,
                             int* __restrict__ order) {
  __shared__ int bs[8];
  int lane = threadIdx.x;                            // 64 threads = 1 wave
  if (lane < 8) bs[lane] = bstart[blockIdx.x * 8 + lane];
  __syncthreads();
  int t = blockIdx.x * 64 + lane;
  int e = best[t];
  unsigned long long lt = (1ull << lane) - 1ull;
  int rank = 0;
  #pragma unroll
  for (int q = 0; q < 8; ++q) {
    unsigned long long m = __ballot(e == q);
    if (e == q) rank = __popcll(m & lt);
  }
  order[bs[e] + rank] = t;
}

// ---- gather: Ag[i][k] = bf16(x[order[i]][k]), one row per block ----
__global__ __launch_bounds__(256) void gather_kernel(const float* __restrict__ x,
                                                     const int* __restrict__ order,
                                                     unsigned short* __restrict__ Ag) {
  const int row = blockIdx.x;
  const int t = threadIdx.x;
  const float4* src = (const float4*)(x + (size_t)order[row] * H_DIM) + t * 2;
  float4 a = src[0], b = src[1];
  uint4 o = make_uint4(pk2(a.x, a.y), pk2(a.z, a.w), pk2(b.x, b.y), pk2(b.z, b.w));
  *((uint4*)(Ag + (size_t)row * H_DIM) + t) = o;
}

// ---- GEMM: m97 structure — 128x128 tile, BK=64, global_load_lds x16, 2 barriers ----
__global__ __launch_bounds__(256) void gemm_kernel(
    const unsigned short* __restrict__ Ag, const unsigned short* __restrict__ WeT,
    const float* __restrict__ be, const float* __restrict__ bestp,
    float* __restrict__ out)
{
  __shared__ __align__(16) unsigned short As[BM * BK];   // 16 KB, linear (gload_lds)
  __shared__ __align__(16) unsigned short Bs[BN * BK];   // 16 KB

  const int tid = threadIdx.x;
  // XCD-bijective swizzle: nwg=2048, 8 XCDs, 256 wg each
  const int bid = blockIdx.x;
  const int wg = (bid & 7) * 256 + (bid >> 3);
  const int m0 = (wg >> 4) * BM;          // 128 M-tiles
  const int n0 = (wg & 15) * BN;          // 16 N-tiles

  const int lane = tid & 63;
  const int wave = tid >> 6;
  const int wm = (wave >> 1) * 64;
  const int wn = (wave & 1) * 64;
  const int fr = lane & 15;
  const int fq = lane >> 4;

  // staging: issue i covers flat bf16 elems [i*2048, i*2048+2048): 32 rows of 64
  const int srow = tid >> 3;              // 0..31 within issue
  const int scol = (tid & 7) * 8;
  const unsigned short* ga = Ag + (size_t)(m0 + srow) * H_DIM + scol;
  const unsigned short* gb = WeT + (size_t)(n0 + srow) * H_DIM + scol;
  char* lA = (char*)As + wave * 1024;     // + issue*4096; lane*16 implicit
  char* lB = (char*)Bs + wave * 1024;

  f32x4 acc[4][4] = {};

  for (int kk = 0; kk < H_DIM; kk += BK) {
    __syncthreads();                      // previous iter's frag reads done
    #pragma unroll
    for (int i = 0; i < 4; ++i) {
      GLOAD16(ga + kk + i * (32 * H_DIM), lA + i * 4096);
      GLOAD16(gb + kk + i * (32 * H_DIM), lB + i * 4096);
    }
    __syncthreads();                      // drains vmcnt -> tile visible
    #pragma unroll
    for (int ks = 0; ks < 2; ++ks) {
      bf16x8 af[4], bfr[4];
      #pragma unroll
      for (int i = 0; i < 4; ++i) {
        af[i]  = *(const bf16x8*)&As[(wm + i * 16 + fr) * BK + fq * 8 + ks * 32];
        bfr[i] = *(const bf16x8*)&Bs[(wn + i * 16 + fr) * BK + fq * 8 + ks * 32];
      }
      #pragma unroll
      for (int mi = 0; mi < 4; ++mi)
        #pragma unroll
        for (int ni = 0; ni < 4; ++ni)
          acc[mi][ni] = __builtin_amdgcn_mfma_f32_16x16x32_bf16(af[mi], bfr[ni], acc[mi][ni], 0, 0, 0);
    }
  }

  float bev[4], sc[4][4];
  #pragma unroll
  for (int ni = 0; ni < 4; ++ni) bev[ni] = be[n0 + wn + ni * 16 + fr];
  #pragma unroll
  for (int mi = 0; mi < 4; ++mi)
    #pragma unroll
    for (int r = 0; r < 4; ++r)
      sc[mi][r] = bestp[m0 + wm + mi * 16 + fq * 4 + r];   // original-order index = out row

  #pragma unroll
  for (int mi = 0; mi < 4; ++mi) {
    #pragma unroll
    for (int ni = 0; ni < 4; ++ni) {
      const int col = n0 + wn + ni * 16 + fr;
      #pragma unroll
      for (int r = 0; r < 4; ++r) {
        const int lrow = wm + mi * 16 + fq * 4 + r;   // C/D: row=(lane>>4)*4+reg, col=lane&15
        out[(size_t)(m0 + lrow) * H_DIM + col] = (acc[mi][ni][r] + bev[ni]) * sc[mi][r];
      }
    }
  }
}

extern "C" void kernel_launch(void* const* d_in, const int* in_sizes, int n_in,
                              void* d_out, int out_size, void* d_ws, size_t ws_size,
                              hipStream_t stream)
{
  const float* x  = (const float*)d_in[0];
  const float* Wg = (const float*)d_in[1];
  const float* bg = (const float*)d_in[2];
  const float* We = (const float*)d_in[3];
  const float* be = (const float*)d_in[4];
  float* out = (float*)d_out;

  char* w = (char*)d_ws;
  int*   best   = (int*)(w);                       // 64 KB
  float* bestp  = (float*)(w + (64 << 10));        // 64 KB
  int*   order  = (int*)(w + (128 << 10));         // 64 KB
  int*   bcnt   = (int*)(w + (192 << 10));         // 8 KB
  int*   bstart = (int*)(w + (200 << 10));         // 8 KB
  float* WgT    = (float*)(w + (208 << 10));       // 64 KB
  unsigned short* WeT = (unsigned short*)(w + (272 << 10));          // 8 MB
  unsigned short* Ag  = (unsigned short*)(w + (272 << 10) + (8u << 20)); // 64 MB

  hipMemsetAsync(bcnt, 0, 2048 * sizeof(int), stream);
  transpose_wg_kernel<<<64, 256, 0, stream>>>(Wg, WgT);
  transpose_we_kernel<<<dim3(64, 64), dim3(32, 8), 0, stream>>>(We, WeT);
  router_kernel<<<2048, 256, 0, stream>>>(x, WgT, bg, best, bestp, bcnt);
  scan_kernel<<<1, 512, 0, stream>>>(bcnt, bstart);
  order_kernel<<<256, 64, 0, stream>>>(best, bstart, order);
  gather_kernel<<<16384, 256, 0, stream>>>(x, order, Ag);
  gemm_kernel<<<2048, 256, 0, stream>>>(Ag, WeT, be, bestp, out);
}